// Round 16
// baseline (152.880 us; speedup 1.0000x reference)
//
#include <hip/hip_runtime.h>
#include <hip/hip_bf16.h>
#include <hip/hip_fp16.h>

#define N_NODES 50000
#define N_EDGES 20000
#define EDGE_K  32
#define CH      256
#define N_INC   (N_EDGES * EDGE_K)   // 640000 incidences
#define ELL_CAP 64                   // max node degree capacity (Poisson(12.8))
#define NSLICE  8                    // channel slices == XCD count
#define SCH     32                   // channels per slice (32 x 2B = 64B rows)
#define ZROW    0x4E4E               // 20046: repeated-byte pattern -> memset prefill
#define EROWS   20047                // yb rows per slice (incl. zero row at 20046)

typedef __attribute__((ext_vector_type(4))) float f32x4;
typedef __attribute__((ext_vector_type(8))) _Float16 f16x8;

static __device__ __forceinline__ __half2 u2h2(unsigned int u) {
    __half2 h; __builtin_memcpy(&h, &u, 4); return h;
}
static __device__ __forceinline__ unsigned int h22u(__half2 h) {
    unsigned int u; __builtin_memcpy(&u, &h, 4); return u;
}
static __device__ __forceinline__ unsigned int pk2h(float a, float b) {
    return h22u(__halves2half2(__float2half_rn(a), __float2half_rn(b)));
}

// Fused prep with INTERLEAVED fill (1 fill : 3 other by blockIdx&3 -> latency-bound
// fill waves co-resident with BW-bound conv waves = true overlap):
//   fill: 2000 bodies, XCD-partitioned ELL build (deg pre-zeroed, ell pre-memset)
//   conv: x->fp16 sliced [8][N][32] | wt: W^T fp16 | last: yb zero-row
#define FILL_GROUPS   8
#define NODES_PER_GRP (N_NODES / FILL_GROUPS)
#define FILL_WIN      2560
#define FILL_BODIES   ((N_INC / FILL_WIN) * FILL_GROUPS) // 2000
#define CONV_BLOCKS   (N_NODES * CH / 8 / 256)           // 6250
#define PREP_GRID     8507   // 8000 interleaved (2000 fill + 6000 other) + 507 tail
__global__ void prep_kernel(const float* __restrict__ x, unsigned short* __restrict__ xb,
                            const float* __restrict__ w, unsigned short* __restrict__ wt,
                            const int* __restrict__ he, int* __restrict__ deg,
                            unsigned short* __restrict__ ell, unsigned short* __restrict__ yb) {
    int b = blockIdx.x;
    if (b < 8000 && (b & 3) == 3) {
        int fb = b >> 2;                      // 0..1999
        int g  = fb & 7;                      // node-range group == XCD heuristic
        int wn = fb >> 3;
        int lo = g * NODES_PER_GRP, hi = lo + NODES_PER_GRP;
        int base = wn * FILL_WIN;
#pragma unroll
        for (int it = 0; it < FILL_WIN / 256; ++it) {
            int i = base + it * 256 + threadIdx.x;
            int node = he[i];
            if (node >= lo && node < hi) {
                int slot = atomicAdd(&deg[node], 1);
                if (slot < ELL_CAP)
                    ell[(size_t)node * ELL_CAP + slot] = (unsigned short)(i >> 5);
            }
        }
        return;
    }
    int cb = (b < 8000) ? (b - (b >> 2)) : (b - 2000);   // 0..6506
    if (cb < CONV_BLOCKS) {
        int i = cb * 256 + threadIdx.x;       // one per 8 channels
        int n = i >> 5, sub = i & 31;
        int g = sub >> 2, cp = (sub & 3) * 8;
        const float* src = x + (size_t)n * CH + sub * 8;
        f32x4 v0 = *reinterpret_cast<const f32x4*>(src);
        f32x4 v1 = *reinterpret_cast<const f32x4*>(src + 4);
        uint4 u;
        u.x = pk2h(v0.x, v0.y);
        u.y = pk2h(v0.z, v0.w);
        u.z = pk2h(v1.x, v1.y);
        u.w = pk2h(v1.z, v1.w);
        *reinterpret_cast<uint4*>(xb + ((size_t)g * N_NODES + n) * SCH + cp) = u;
    } else if (cb < CONV_BLOCKS + CH) {
        int n = cb - CONV_BLOCKS;
        int k = threadIdx.x;
        __half h = __float2half_rn(w[k * CH + n]);
        wt[n * CH + k] = *reinterpret_cast<unsigned short*>(&h);
    } else if (cb == CONV_BLOCKS + CH) {
        // zero the dedicated yb zero-row for each slice (8 x 32 halves = 256)
        int g = threadIdx.x >> 5, c = threadIdx.x & 31;
        yb[((size_t)g * EROWS + ZROW) * SCH + c] = 0;
    }
}

// Pure sliced gather (R10 shape): wave = 4 edges x slice g=blockIdx&7 (3.2MB
// slice L2-resident). Lanes (ep=l>>4, k=(l>>2)&3, q=l&3); 8 batched 16B loads.
#define GATHER_BLOCKS ((N_EDGES / 16) * NSLICE)          // 10000
__global__ __launch_bounds__(256, 4) void gather_kernel(
        const unsigned short* __restrict__ xb, const int* __restrict__ he,
        unsigned short* __restrict__ es) {
    int gb  = blockIdx.x;
    int g   = gb & 7;                 // slice == XCD (round-robin heuristic)
    int grp = gb >> 3;
    int w = threadIdx.x >> 6, lane = threadIdx.x & 63;
    int ebase = grp * 16 + w * 4;     // this wave's 4 edges
    const int* hp = he + (size_t)ebase * EDGE_K;
    int s = lane & 15;
    int ep = lane >> 4, k = (lane >> 2) & 3, q = lane & 3;
    int mA = hp[ep * 32 + s];         // edge ep, node slots 0..15
    int mB = hp[ep * 32 + 16 + s];    // edge ep, node slots 16..31
    const unsigned short* xg = xb + (size_t)g * N_NODES * SCH;
    int hb = lane & 48;
    int e0 = __shfl(mA, hb + ((0 + k) & 15), 64);
    int e1 = __shfl(mA, hb + ((4 + k) & 15), 64);
    int e2 = __shfl(mA, hb + ((8 + k) & 15), 64);
    int e3 = __shfl(mA, hb + ((12 + k) & 15), 64);
    int e4 = __shfl(mB, hb + ((0 + k) & 15), 64);
    int e5 = __shfl(mB, hb + ((4 + k) & 15), 64);
    int e6 = __shfl(mB, hb + ((8 + k) & 15), 64);
    int e7 = __shfl(mB, hb + ((12 + k) & 15), 64);
    uint4 d0 = *reinterpret_cast<const uint4*>(xg + (size_t)e0 * SCH + q * 8);
    uint4 d1 = *reinterpret_cast<const uint4*>(xg + (size_t)e1 * SCH + q * 8);
    uint4 d2 = *reinterpret_cast<const uint4*>(xg + (size_t)e2 * SCH + q * 8);
    uint4 d3 = *reinterpret_cast<const uint4*>(xg + (size_t)e3 * SCH + q * 8);
    uint4 d4 = *reinterpret_cast<const uint4*>(xg + (size_t)e4 * SCH + q * 8);
    uint4 d5 = *reinterpret_cast<const uint4*>(xg + (size_t)e5 * SCH + q * 8);
    uint4 d6 = *reinterpret_cast<const uint4*>(xg + (size_t)e6 * SCH + q * 8);
    uint4 d7 = *reinterpret_cast<const uint4*>(xg + (size_t)e7 * SCH + q * 8);
    __half2 a0 = u2h2(0u), a1 = u2h2(0u), a2 = u2h2(0u), a3 = u2h2(0u);
    a0 = __hadd2(a0, u2h2(d0.x)); a1 = __hadd2(a1, u2h2(d0.y));
    a2 = __hadd2(a2, u2h2(d0.z)); a3 = __hadd2(a3, u2h2(d0.w));
    a0 = __hadd2(a0, u2h2(d1.x)); a1 = __hadd2(a1, u2h2(d1.y));
    a2 = __hadd2(a2, u2h2(d1.z)); a3 = __hadd2(a3, u2h2(d1.w));
    a0 = __hadd2(a0, u2h2(d2.x)); a1 = __hadd2(a1, u2h2(d2.y));
    a2 = __hadd2(a2, u2h2(d2.z)); a3 = __hadd2(a3, u2h2(d2.w));
    a0 = __hadd2(a0, u2h2(d3.x)); a1 = __hadd2(a1, u2h2(d3.y));
    a2 = __hadd2(a2, u2h2(d3.z)); a3 = __hadd2(a3, u2h2(d3.w));
    a0 = __hadd2(a0, u2h2(d4.x)); a1 = __hadd2(a1, u2h2(d4.y));
    a2 = __hadd2(a2, u2h2(d4.z)); a3 = __hadd2(a3, u2h2(d4.w));
    a0 = __hadd2(a0, u2h2(d5.x)); a1 = __hadd2(a1, u2h2(d5.y));
    a2 = __hadd2(a2, u2h2(d5.z)); a3 = __hadd2(a3, u2h2(d5.w));
    a0 = __hadd2(a0, u2h2(d6.x)); a1 = __hadd2(a1, u2h2(d6.y));
    a2 = __hadd2(a2, u2h2(d6.z)); a3 = __hadd2(a3, u2h2(d6.w));
    a0 = __hadd2(a0, u2h2(d7.x)); a1 = __hadd2(a1, u2h2(d7.y));
    a2 = __hadd2(a2, u2h2(d7.z)); a3 = __hadd2(a3, u2h2(d7.w));
    a0 = __hadd2(a0, u2h2(__shfl_xor(h22u(a0), 4, 64)));
    a1 = __hadd2(a1, u2h2(__shfl_xor(h22u(a1), 4, 64)));
    a2 = __hadd2(a2, u2h2(__shfl_xor(h22u(a2), 4, 64)));
    a3 = __hadd2(a3, u2h2(__shfl_xor(h22u(a3), 4, 64)));
    a0 = __hadd2(a0, u2h2(__shfl_xor(h22u(a0), 8, 64)));
    a1 = __hadd2(a1, u2h2(__shfl_xor(h22u(a1), 8, 64)));
    a2 = __hadd2(a2, u2h2(__shfl_xor(h22u(a2), 8, 64)));
    a3 = __hadd2(a3, u2h2(__shfl_xor(h22u(a3), 8, 64)));
    if ((lane & 12) == 0) {           // k==0 lanes: (ep, q)
        uint4 u;
        u.x = h22u(a0); u.y = h22u(a1); u.z = h22u(a2); u.w = h22u(a3);
        *reinterpret_cast<uint4*>(es + (size_t)(ebase + ep) * CH + g * SCH + q * 8) = u;
    }
}

// Y = es(fp16) @ W(fp16) via mfma_f32_16x16x32_f16; yb stored SLICED [8][EROWS][32]
__global__ __launch_bounds__(256) void gemm_kernel(const unsigned short* __restrict__ es,
                                                   const unsigned short* __restrict__ wt,
                                                   unsigned short* __restrict__ yb) {
    int wid  = threadIdx.x >> 6;
    int lane = threadIdx.x & 63;
    int m0   = blockIdx.x * 64 + wid * 16;
    if (m0 >= N_EDGES) return;
    int lr = lane & 15;
    int lg = lane >> 4;

    f32x4 acc[16] = {};
    const unsigned short* arow = es + (size_t)(m0 + lr) * CH + lg * 8;
#pragma unroll
    for (int kk = 0; kk < CH; kk += 32) {
        f16x8 a = *reinterpret_cast<const f16x8*>(arow + kk);
#pragma unroll
        for (int nt = 0; nt < 16; ++nt) {
            f16x8 bb = *reinterpret_cast<const f16x8*>(
                wt + (size_t)(nt * 16 + lr) * CH + kk + lg * 8);
            acc[nt] = __builtin_amdgcn_mfma_f32_16x16x32_f16(a, bb, acc[nt], 0, 0, 0);
        }
    }
    // D layout: col = lane&15, row = (lane>>4)*4 + r  -> sliced write
#pragma unroll
    for (int nt = 0; nt < 16; ++nt) {
#pragma unroll
        for (int r = 0; r < 4; ++r) {
            int row = m0 + lg * 4 + r;
            __half h = __float2half_rn(acc[nt][r]);
            yb[((size_t)(nt >> 1) * EROWS + row) * SCH + (nt & 1) * 16 + lr] =
                *reinterpret_cast<unsigned short*>(&h);
        }
    }
}

// out[n][g*32..] = relu( sum_j yb[g][ell[n][j]][:] ) -- sliced, XCD-pinned.
// ELL memset-prefilled to ZROW -> UNCONDITIONAL loads; rounds by wave-uniform dmax.
#define AP_NPB    16                               // nodes per block (4 waves x 4)
#define AP_BLOCKS ((N_NODES / AP_NPB) * NSLICE)    // 25000
__global__ __launch_bounds__(256, 4) void apply_kernel(
        const unsigned short* __restrict__ yb, const int* __restrict__ deg,
        const unsigned short* __restrict__ ell, float* __restrict__ out) {
    int b = blockIdx.x;
    int g = b & 7;                    // slice == XCD
    int w = threadIdx.x >> 6, lane = threadIdx.x & 63;
    int np = lane >> 4, s = lane & 15, k = (lane >> 2) & 3, q = lane & 3;
    int node = (b >> 3) * AP_NPB + w * 4 + np;     // exact cover
    int d = deg[node];
    const unsigned short* er = ell + (size_t)node * ELL_CAP;
    int m0 = er[s], m1 = er[16 + s];
    int dmax = d;
    dmax = max(dmax, __shfl_xor(dmax, 16, 64));
    dmax = max(dmax, __shfl_xor(dmax, 32, 64));    // wave-uniform max degree
    const unsigned short* yg = yb + (size_t)g * EROWS * SCH;
    int hb = lane & 48;
    // round 1: slots 0..15 unconditional (slack slots -> hot ZROW line)
    int e0 = __shfl(m0, hb + 0 + k, 64);
    int e1 = __shfl(m0, hb + 4 + k, 64);
    int e2 = __shfl(m0, hb + 8 + k, 64);
    int e3 = __shfl(m0, hb + 12 + k, 64);
    uint4 d0 = *reinterpret_cast<const uint4*>(yg + (size_t)e0 * SCH + q * 8);
    uint4 d1 = *reinterpret_cast<const uint4*>(yg + (size_t)e1 * SCH + q * 8);
    uint4 d2 = *reinterpret_cast<const uint4*>(yg + (size_t)e2 * SCH + q * 8);
    uint4 d3 = *reinterpret_cast<const uint4*>(yg + (size_t)e3 * SCH + q * 8);
    __half2 a0 = __hadd2(u2h2(d0.x), u2h2(d1.x));
    __half2 a1 = __hadd2(u2h2(d0.y), u2h2(d1.y));
    __half2 a2 = __hadd2(u2h2(d0.z), u2h2(d1.z));
    __half2 a3 = __hadd2(u2h2(d0.w), u2h2(d1.w));
    a0 = __hadd2(a0, u2h2(d2.x)); a1 = __hadd2(a1, u2h2(d2.y));
    a2 = __hadd2(a2, u2h2(d2.z)); a3 = __hadd2(a3, u2h2(d2.w));
    a0 = __hadd2(a0, u2h2(d3.x)); a1 = __hadd2(a1, u2h2(d3.y));
    a2 = __hadd2(a2, u2h2(d3.z)); a3 = __hadd2(a3, u2h2(d3.w));
    if (dmax > 16) {                  // round 2: slots 16..31 (~35% of waves)
        int f0 = __shfl(m1, hb + 0 + k, 64);
        int f1 = __shfl(m1, hb + 4 + k, 64);
        int f2 = __shfl(m1, hb + 8 + k, 64);
        int f3 = __shfl(m1, hb + 12 + k, 64);
        uint4 c0 = *reinterpret_cast<const uint4*>(yg + (size_t)f0 * SCH + q * 8);
        uint4 c1 = *reinterpret_cast<const uint4*>(yg + (size_t)f1 * SCH + q * 8);
        uint4 c2 = *reinterpret_cast<const uint4*>(yg + (size_t)f2 * SCH + q * 8);
        uint4 c3 = *reinterpret_cast<const uint4*>(yg + (size_t)f3 * SCH + q * 8);
        a0 = __hadd2(a0, u2h2(c0.x)); a1 = __hadd2(a1, u2h2(c0.y));
        a2 = __hadd2(a2, u2h2(c0.z)); a3 = __hadd2(a3, u2h2(c0.w));
        a0 = __hadd2(a0, u2h2(c1.x)); a1 = __hadd2(a1, u2h2(c1.y));
        a2 = __hadd2(a2, u2h2(c1.z)); a3 = __hadd2(a3, u2h2(c1.w));
        a0 = __hadd2(a0, u2h2(c2.x)); a1 = __hadd2(a1, u2h2(c2.y));
        a2 = __hadd2(a2, u2h2(c2.z)); a3 = __hadd2(a3, u2h2(c2.w));
        a0 = __hadd2(a0, u2h2(c3.x)); a1 = __hadd2(a1, u2h2(c3.y));
        a2 = __hadd2(a2, u2h2(c3.z)); a3 = __hadd2(a3, u2h2(c3.w));
    }
    if (dmax > 32) {                  // rare (P ~ 1e-5 per wave)
        int m2 = er[32 + s], m3 = er[48 + s];
#pragma unroll
        for (int rq = 0; rq < 2; ++rq) {
            int m = rq ? m3 : m2;
            int f0 = __shfl(m, hb + 0 + k, 64);
            int f1 = __shfl(m, hb + 4 + k, 64);
            int f2 = __shfl(m, hb + 8 + k, 64);
            int f3 = __shfl(m, hb + 12 + k, 64);
            uint4 c0 = *reinterpret_cast<const uint4*>(yg + (size_t)f0 * SCH + q * 8);
            uint4 c1 = *reinterpret_cast<const uint4*>(yg + (size_t)f1 * SCH + q * 8);
            uint4 c2 = *reinterpret_cast<const uint4*>(yg + (size_t)f2 * SCH + q * 8);
            uint4 c3 = *reinterpret_cast<const uint4*>(yg + (size_t)f3 * SCH + q * 8);
            a0 = __hadd2(a0, u2h2(c0.x)); a1 = __hadd2(a1, u2h2(c0.y));
            a2 = __hadd2(a2, u2h2(c0.z)); a3 = __hadd2(a3, u2h2(c0.w));
            a0 = __hadd2(a0, u2h2(c1.x)); a1 = __hadd2(a1, u2h2(c1.y));
            a2 = __hadd2(a2, u2h2(c1.z)); a3 = __hadd2(a3, u2h2(c1.w));
            a0 = __hadd2(a0, u2h2(c2.x)); a1 = __hadd2(a1, u2h2(c2.y));
            a2 = __hadd2(a2, u2h2(c2.z)); a3 = __hadd2(a3, u2h2(c2.w));
            a0 = __hadd2(a0, u2h2(c3.x)); a1 = __hadd2(a1, u2h2(c3.y));
            a2 = __hadd2(a2, u2h2(c3.z)); a3 = __hadd2(a3, u2h2(c3.w));
        }
    }
    // reduce over k (4 lanes)
    a0 = __hadd2(a0, u2h2(__shfl_xor(h22u(a0), 4, 64)));
    a1 = __hadd2(a1, u2h2(__shfl_xor(h22u(a1), 4, 64)));
    a2 = __hadd2(a2, u2h2(__shfl_xor(h22u(a2), 4, 64)));
    a3 = __hadd2(a3, u2h2(__shfl_xor(h22u(a3), 4, 64)));
    a0 = __hadd2(a0, u2h2(__shfl_xor(h22u(a0), 8, 64)));
    a1 = __hadd2(a1, u2h2(__shfl_xor(h22u(a1), 8, 64)));
    a2 = __hadd2(a2, u2h2(__shfl_xor(h22u(a2), 8, 64)));
    a3 = __hadd2(a3, u2h2(__shfl_xor(h22u(a3), 8, 64)));
    if ((lane & 12) == 0) {           // k==0 lanes: (np, q)
        float2 f0 = __half22float2(a0);
        float2 f1 = __half22float2(a1);
        float2 f2 = __half22float2(a2);
        float2 f3 = __half22float2(a3);
        f32x4 r0, r1;
        r0.x = fmaxf(f0.x, 0.f); r0.y = fmaxf(f0.y, 0.f);
        r0.z = fmaxf(f1.x, 0.f); r0.w = fmaxf(f1.y, 0.f);
        r1.x = fmaxf(f2.x, 0.f); r1.y = fmaxf(f2.y, 0.f);
        r1.z = fmaxf(f3.x, 0.f); r1.w = fmaxf(f3.y, 0.f);
        float* dst = out + (size_t)node * CH + g * SCH + q * 8;
        *reinterpret_cast<f32x4*>(dst)     = r0;
        *reinterpret_cast<f32x4*>(dst + 4) = r1;
    }
}

extern "C" void kernel_launch(void* const* d_in, const int* in_sizes, int n_in,
                              void* d_out, int out_size, void* d_ws, size_t ws_size,
                              hipStream_t stream) {
    const float* x  = (const float*)d_in[0];
    const int*   he = (const int*)d_in[1];
    const float* w  = (const float*)d_in[2];
    float* out = (float*)d_out;

    // workspace layout
    char* ws = (char*)d_ws;
    unsigned short* wt  = (unsigned short*)ws;                        // 131072 B
    unsigned short* es  = (unsigned short*)(ws + 131072);             // 10240000 B
    unsigned short* yb  = (unsigned short*)(ws + 10371072);           // 8*20047*32*2 = 10264064 B
    int* deg = (int*)(ws + 20635136);                                 // 200000 B
    unsigned short* ell = (unsigned short*)(ws + 20835136);           // 6400000 B

    // xb (fp16 x, sliced [8][N][32], 25.6 MB) lives inside d_out (51.2 MB f32)
    unsigned short* xb = (unsigned short*)d_out;

    hipMemsetAsync(deg, 0, (size_t)N_NODES * 4, stream);
    hipMemsetAsync(ell, 0x4E, (size_t)N_NODES * ELL_CAP * 2, stream);  // prefill = ZROW

    prep_kernel<<<PREP_GRID, 256, 0, stream>>>(x, xb, w, wt, he, deg, ell, yb);

    gather_kernel<<<GATHER_BLOCKS, 256, 0, stream>>>(xb, he, es);

    {
        int blocks = (N_EDGES + 63) / 64;
        gemm_kernel<<<blocks, 256, 0, stream>>>(es, wt, yb);
    }

    apply_kernel<<<AP_BLOCKS, 256, 0, stream>>>(yb, deg, ell, out);
}

// Round 17
// 146.261 us; speedup vs baseline: 1.0453x; 1.0453x over previous
//
#include <hip/hip_runtime.h>
#include <hip/hip_bf16.h>
#include <hip/hip_fp16.h>

#define N_NODES 50000
#define N_EDGES 20000
#define EDGE_K  32
#define CH      256
#define N_INC   (N_EDGES * EDGE_K)   // 640000 incidences
#define ELL_CAP 64                   // max node degree capacity (Poisson(12.8))
#define NSLICE  8                    // channel slices == XCD count
#define SCH     32                   // channels per slice (32 x 2B = 64B rows)
#define ZROW    N_EDGES              // dedicated all-zeros yb row (clamp target)

typedef __attribute__((ext_vector_type(4))) float f32x4;
typedef __attribute__((ext_vector_type(8))) _Float16 f16x8;

static __device__ __forceinline__ __half2 u2h2(unsigned int u) {
    __half2 h; __builtin_memcpy(&h, &u, 4); return h;
}
static __device__ __forceinline__ unsigned int h22u(__half2 h) {
    unsigned int u; __builtin_memcpy(&u, &h, 4); return u;
}
static __device__ __forceinline__ unsigned int pk2h(float a, float b) {
    return h22u(__halves2half2(__float2half_rn(a), __float2half_rn(b)));
}

// Slim prep: [0,CONV) x->fp16 sliced [8][N][32] | [+CH) W^T fp16 | [last] yb zero-row
// (deg zeroed by memsetAsync; no ELL prefill needed — apply clamps in-register)
#define CONV_BLOCKS (N_NODES * CH / 8 / 256)           // 6250
__global__ void prep_kernel(const float* __restrict__ x, unsigned short* __restrict__ xb,
                            const float* __restrict__ w, unsigned short* __restrict__ wt,
                            unsigned short* __restrict__ yb) {
    int b = blockIdx.x;
    if (b < CONV_BLOCKS) {
        int i = b * 256 + threadIdx.x;        // one per 8 channels
        int n = i >> 5, sub = i & 31;
        int g = sub >> 2, cp = (sub & 3) * 8;
        const float* src = x + (size_t)n * CH + sub * 8;
        f32x4 v0 = *reinterpret_cast<const f32x4*>(src);
        f32x4 v1 = *reinterpret_cast<const f32x4*>(src + 4);
        uint4 u;
        u.x = pk2h(v0.x, v0.y);
        u.y = pk2h(v0.z, v0.w);
        u.z = pk2h(v1.x, v1.y);
        u.w = pk2h(v1.z, v1.w);
        *reinterpret_cast<uint4*>(xb + ((size_t)g * N_NODES + n) * SCH + cp) = u;
    } else if (b < CONV_BLOCKS + CH) {
        int n = b - CONV_BLOCKS;
        int k = threadIdx.x;
        __half h = __float2half_rn(w[k * CH + n]);
        wt[n * CH + k] = *reinterpret_cast<unsigned short*>(&h);
    } else {
        // zero the dedicated yb zero-row for each slice (8 x 32 halves = 256)
        int g = threadIdx.x >> 5, c = threadIdx.x & 31;
        yb[((size_t)g * (N_EDGES + 1) + ZROW) * SCH + c] = 0;
    }
}

// Fused: ELL-fill (head, XCD-partitioned, BATCHED index loads) + sliced gather
// (tail) — R10 structure. Gather wave = 4 edges x slice g=blockIdx&7 (3.2MB
// slice L2-resident). Lanes (ep=l>>4, k=(l>>2)&3, q=l&3); 8 batched 16B loads.
#define FILL_GROUPS   8
#define NODES_PER_GRP (N_NODES / FILL_GROUPS)
#define FILL_WIN      2560
#define FILL_BLOCKS   ((N_INC / FILL_WIN) * FILL_GROUPS) // 2000
#define GATHER_BLOCKS ((N_EDGES / 16) * NSLICE)          // 10000
__global__ __launch_bounds__(256, 4) void gather_fill_kernel(
        const unsigned short* __restrict__ xb, const int* __restrict__ he,
        unsigned short* __restrict__ es, int* __restrict__ deg,
        unsigned short* __restrict__ ell) {
    int b = blockIdx.x;
    if (b < FILL_BLOCKS) {
        int g  = b & 7;                       // node-range group == XCD heuristic
        int wn = b >> 3;
        int lo = g * NODES_PER_GRP, hi = lo + NODES_PER_GRP;
        int base = wn * FILL_WIN + threadIdx.x;
        int idx[FILL_WIN / 256];              // batch all 10 index loads upfront
#pragma unroll
        for (int it = 0; it < FILL_WIN / 256; ++it) idx[it] = he[base + it * 256];
#pragma unroll
        for (int it = 0; it < FILL_WIN / 256; ++it) {
            int node = idx[it];
            if (node >= lo && node < hi) {
                int slot = atomicAdd(&deg[node], 1);
                if (slot < ELL_CAP)
                    ell[(size_t)node * ELL_CAP + slot] =
                        (unsigned short)((base + it * 256) >> 5);
            }
        }
        return;
    }
    int gb  = b - FILL_BLOCKS;
    int g   = gb & 7;                 // slice == XCD (round-robin heuristic)
    int grp = gb >> 3;
    int w = threadIdx.x >> 6, lane = threadIdx.x & 63;
    int ebase = grp * 16 + w * 4;     // this wave's 4 edges
    const int* hp = he + (size_t)ebase * EDGE_K;
    int s = lane & 15;
    int ep = lane >> 4, k = (lane >> 2) & 3, q = lane & 3;
    int mA = hp[ep * 32 + s];         // edge ep, node slots 0..15
    int mB = hp[ep * 32 + 16 + s];    // edge ep, node slots 16..31
    const unsigned short* xg = xb + (size_t)g * N_NODES * SCH;
    int hb = lane & 48;
    int e0 = __shfl(mA, hb + ((0 + k) & 15), 64);
    int e1 = __shfl(mA, hb + ((4 + k) & 15), 64);
    int e2 = __shfl(mA, hb + ((8 + k) & 15), 64);
    int e3 = __shfl(mA, hb + ((12 + k) & 15), 64);
    int e4 = __shfl(mB, hb + ((0 + k) & 15), 64);
    int e5 = __shfl(mB, hb + ((4 + k) & 15), 64);
    int e6 = __shfl(mB, hb + ((8 + k) & 15), 64);
    int e7 = __shfl(mB, hb + ((12 + k) & 15), 64);
    uint4 d0 = *reinterpret_cast<const uint4*>(xg + (size_t)e0 * SCH + q * 8);
    uint4 d1 = *reinterpret_cast<const uint4*>(xg + (size_t)e1 * SCH + q * 8);
    uint4 d2 = *reinterpret_cast<const uint4*>(xg + (size_t)e2 * SCH + q * 8);
    uint4 d3 = *reinterpret_cast<const uint4*>(xg + (size_t)e3 * SCH + q * 8);
    uint4 d4 = *reinterpret_cast<const uint4*>(xg + (size_t)e4 * SCH + q * 8);
    uint4 d5 = *reinterpret_cast<const uint4*>(xg + (size_t)e5 * SCH + q * 8);
    uint4 d6 = *reinterpret_cast<const uint4*>(xg + (size_t)e6 * SCH + q * 8);
    uint4 d7 = *reinterpret_cast<const uint4*>(xg + (size_t)e7 * SCH + q * 8);
    __half2 a0 = u2h2(0u), a1 = u2h2(0u), a2 = u2h2(0u), a3 = u2h2(0u);
    a0 = __hadd2(a0, u2h2(d0.x)); a1 = __hadd2(a1, u2h2(d0.y));
    a2 = __hadd2(a2, u2h2(d0.z)); a3 = __hadd2(a3, u2h2(d0.w));
    a0 = __hadd2(a0, u2h2(d1.x)); a1 = __hadd2(a1, u2h2(d1.y));
    a2 = __hadd2(a2, u2h2(d1.z)); a3 = __hadd2(a3, u2h2(d1.w));
    a0 = __hadd2(a0, u2h2(d2.x)); a1 = __hadd2(a1, u2h2(d2.y));
    a2 = __hadd2(a2, u2h2(d2.z)); a3 = __hadd2(a3, u2h2(d2.w));
    a0 = __hadd2(a0, u2h2(d3.x)); a1 = __hadd2(a1, u2h2(d3.y));
    a2 = __hadd2(a2, u2h2(d3.z)); a3 = __hadd2(a3, u2h2(d3.w));
    a0 = __hadd2(a0, u2h2(d4.x)); a1 = __hadd2(a1, u2h2(d4.y));
    a2 = __hadd2(a2, u2h2(d4.z)); a3 = __hadd2(a3, u2h2(d4.w));
    a0 = __hadd2(a0, u2h2(d5.x)); a1 = __hadd2(a1, u2h2(d5.y));
    a2 = __hadd2(a2, u2h2(d5.z)); a3 = __hadd2(a3, u2h2(d5.w));
    a0 = __hadd2(a0, u2h2(d6.x)); a1 = __hadd2(a1, u2h2(d6.y));
    a2 = __hadd2(a2, u2h2(d6.z)); a3 = __hadd2(a3, u2h2(d6.w));
    a0 = __hadd2(a0, u2h2(d7.x)); a1 = __hadd2(a1, u2h2(d7.y));
    a2 = __hadd2(a2, u2h2(d7.z)); a3 = __hadd2(a3, u2h2(d7.w));
    a0 = __hadd2(a0, u2h2(__shfl_xor(h22u(a0), 4, 64)));
    a1 = __hadd2(a1, u2h2(__shfl_xor(h22u(a1), 4, 64)));
    a2 = __hadd2(a2, u2h2(__shfl_xor(h22u(a2), 4, 64)));
    a3 = __hadd2(a3, u2h2(__shfl_xor(h22u(a3), 4, 64)));
    a0 = __hadd2(a0, u2h2(__shfl_xor(h22u(a0), 8, 64)));
    a1 = __hadd2(a1, u2h2(__shfl_xor(h22u(a1), 8, 64)));
    a2 = __hadd2(a2, u2h2(__shfl_xor(h22u(a2), 8, 64)));
    a3 = __hadd2(a3, u2h2(__shfl_xor(h22u(a3), 8, 64)));
    if ((lane & 12) == 0) {           // k==0 lanes: (ep, q)
        uint4 u;
        u.x = h22u(a0); u.y = h22u(a1); u.z = h22u(a2); u.w = h22u(a3);
        *reinterpret_cast<uint4*>(es + (size_t)(ebase + ep) * CH + g * SCH + q * 8) = u;
    }
}

// Y = es(fp16) @ W(fp16) via mfma_f32_16x16x32_f16; yb stored SLICED [8][E+1][32]
__global__ __launch_bounds__(256) void gemm_kernel(const unsigned short* __restrict__ es,
                                                   const unsigned short* __restrict__ wt,
                                                   unsigned short* __restrict__ yb) {
    int wid  = threadIdx.x >> 6;
    int lane = threadIdx.x & 63;
    int m0   = blockIdx.x * 64 + wid * 16;
    if (m0 >= N_EDGES) return;
    int lr = lane & 15;
    int lg = lane >> 4;

    f32x4 acc[16] = {};
    const unsigned short* arow = es + (size_t)(m0 + lr) * CH + lg * 8;
#pragma unroll
    for (int kk = 0; kk < CH; kk += 32) {
        f16x8 a = *reinterpret_cast<const f16x8*>(arow + kk);
#pragma unroll
        for (int nt = 0; nt < 16; ++nt) {
            f16x8 bb = *reinterpret_cast<const f16x8*>(
                wt + (size_t)(nt * 16 + lr) * CH + kk + lg * 8);
            acc[nt] = __builtin_amdgcn_mfma_f32_16x16x32_f16(a, bb, acc[nt], 0, 0, 0);
        }
    }
    // D layout: col = lane&15, row = (lane>>4)*4 + r  -> sliced write
#pragma unroll
    for (int nt = 0; nt < 16; ++nt) {
#pragma unroll
        for (int r = 0; r < 4; ++r) {
            int row = m0 + lg * 4 + r;
            __half h = __float2half_rn(acc[nt][r]);
            yb[((size_t)(nt >> 1) * (N_EDGES + 1) + row) * SCH + (nt & 1) * 16 + lr] =
                *reinterpret_cast<unsigned short*>(&h);
        }
    }
}

// out[n][g*32..] = relu( sum_j yb[g][ell[n][j]][:] ) -- sliced, XCD-pinned,
// ZROW-clamped slots, batched loads (R10's proven apply). Wave = 4 nodes x slice.
#define AP_NPB    16                               // nodes per block (4 waves x 4)
#define AP_BLOCKS ((N_NODES / AP_NPB) * NSLICE)    // 25000
__global__ __launch_bounds__(256, 4) void apply_kernel(
        const unsigned short* __restrict__ yb, const int* __restrict__ deg,
        const unsigned short* __restrict__ ell, float* __restrict__ out) {
    int b = blockIdx.x;
    int g = b & 7;                    // slice == XCD
    int w = threadIdx.x >> 6, lane = threadIdx.x & 63;
    int np = lane >> 4, s = lane & 15, k = (lane >> 2) & 3, q = lane & 3;
    int node = (b >> 3) * AP_NPB + w * 4 + np;     // exact cover
    int d = deg[node];
    if (d > ELL_CAP) d = ELL_CAP;
    const unsigned short* er = ell + (size_t)node * ELL_CAP;
    int m0 = er[s], m1 = er[16 + s];
    int dmax = d;
    dmax = max(dmax, __shfl_xor(dmax, 16, 64));
    dmax = max(dmax, __shfl_xor(dmax, 32, 64));    // wave-uniform max degree
    const unsigned short* yg = yb + (size_t)g * (N_EDGES + 1) * SCH;
    int hb = lane & 48;
    // slots 0..31 in one batch (clamped lanes hit the hot ZROW line)
    int e0 = __shfl(m0, hb + 0 + k, 64);  e0 = (0 + k  < d) ? e0 : ZROW;
    int e1 = __shfl(m0, hb + 4 + k, 64);  e1 = (4 + k  < d) ? e1 : ZROW;
    int e2 = __shfl(m0, hb + 8 + k, 64);  e2 = (8 + k  < d) ? e2 : ZROW;
    int e3 = __shfl(m0, hb + 12 + k, 64); e3 = (12 + k < d) ? e3 : ZROW;
    int e4 = __shfl(m1, hb + 0 + k, 64);  e4 = (16 + k < d) ? e4 : ZROW;
    int e5 = __shfl(m1, hb + 4 + k, 64);  e5 = (20 + k < d) ? e5 : ZROW;
    int e6 = __shfl(m1, hb + 8 + k, 64);  e6 = (24 + k < d) ? e6 : ZROW;
    int e7 = __shfl(m1, hb + 12 + k, 64); e7 = (28 + k < d) ? e7 : ZROW;
    uint4 d0 = *reinterpret_cast<const uint4*>(yg + (size_t)e0 * SCH + q * 8);
    uint4 d1 = *reinterpret_cast<const uint4*>(yg + (size_t)e1 * SCH + q * 8);
    uint4 d2 = *reinterpret_cast<const uint4*>(yg + (size_t)e2 * SCH + q * 8);
    uint4 d3 = *reinterpret_cast<const uint4*>(yg + (size_t)e3 * SCH + q * 8);
    uint4 d4 = *reinterpret_cast<const uint4*>(yg + (size_t)e4 * SCH + q * 8);
    uint4 d5 = *reinterpret_cast<const uint4*>(yg + (size_t)e5 * SCH + q * 8);
    uint4 d6 = *reinterpret_cast<const uint4*>(yg + (size_t)e6 * SCH + q * 8);
    uint4 d7 = *reinterpret_cast<const uint4*>(yg + (size_t)e7 * SCH + q * 8);
    __half2 a0 = u2h2(0u), a1 = u2h2(0u), a2 = u2h2(0u), a3 = u2h2(0u);
    a0 = __hadd2(a0, u2h2(d0.x)); a1 = __hadd2(a1, u2h2(d0.y));
    a2 = __hadd2(a2, u2h2(d0.z)); a3 = __hadd2(a3, u2h2(d0.w));
    a0 = __hadd2(a0, u2h2(d1.x)); a1 = __hadd2(a1, u2h2(d1.y));
    a2 = __hadd2(a2, u2h2(d1.z)); a3 = __hadd2(a3, u2h2(d1.w));
    a0 = __hadd2(a0, u2h2(d2.x)); a1 = __hadd2(a1, u2h2(d2.y));
    a2 = __hadd2(a2, u2h2(d2.z)); a3 = __hadd2(a3, u2h2(d2.w));
    a0 = __hadd2(a0, u2h2(d3.x)); a1 = __hadd2(a1, u2h2(d3.y));
    a2 = __hadd2(a2, u2h2(d3.z)); a3 = __hadd2(a3, u2h2(d3.w));
    a0 = __hadd2(a0, u2h2(d4.x)); a1 = __hadd2(a1, u2h2(d4.y));
    a2 = __hadd2(a2, u2h2(d4.z)); a3 = __hadd2(a3, u2h2(d4.w));
    a0 = __hadd2(a0, u2h2(d5.x)); a1 = __hadd2(a1, u2h2(d5.y));
    a2 = __hadd2(a2, u2h2(d5.z)); a3 = __hadd2(a3, u2h2(d5.w));
    a0 = __hadd2(a0, u2h2(d6.x)); a1 = __hadd2(a1, u2h2(d6.y));
    a2 = __hadd2(a2, u2h2(d6.z)); a3 = __hadd2(a3, u2h2(d6.w));
    a0 = __hadd2(a0, u2h2(d7.x)); a1 = __hadd2(a1, u2h2(d7.y));
    a2 = __hadd2(a2, u2h2(d7.z)); a3 = __hadd2(a3, u2h2(d7.w));
    if (dmax > 32) {                  // rare (P ~ 1e-5 per wave)
        int m2 = er[32 + s], m3 = er[48 + s];
        int f0 = __shfl(m2, hb + 0 + k, 64);  f0 = (32 + k < d) ? f0 : ZROW;
        int f1 = __shfl(m2, hb + 4 + k, 64);  f1 = (36 + k < d) ? f1 : ZROW;
        int f2 = __shfl(m2, hb + 8 + k, 64);  f2 = (40 + k < d) ? f2 : ZROW;
        int f3 = __shfl(m2, hb + 12 + k, 64); f3 = (44 + k < d) ? f3 : ZROW;
        int f4 = __shfl(m3, hb + 0 + k, 64);  f4 = (48 + k < d) ? f4 : ZROW;
        int f5 = __shfl(m3, hb + 4 + k, 64);  f5 = (52 + k < d) ? f5 : ZROW;
        int f6 = __shfl(m3, hb + 8 + k, 64);  f6 = (56 + k < d) ? f6 : ZROW;
        int f7 = __shfl(m3, hb + 12 + k, 64); f7 = (60 + k < d) ? f7 : ZROW;
        uint4 c0 = *reinterpret_cast<const uint4*>(yg + (size_t)f0 * SCH + q * 8);
        uint4 c1 = *reinterpret_cast<const uint4*>(yg + (size_t)f1 * SCH + q * 8);
        uint4 c2 = *reinterpret_cast<const uint4*>(yg + (size_t)f2 * SCH + q * 8);
        uint4 c3 = *reinterpret_cast<const uint4*>(yg + (size_t)f3 * SCH + q * 8);
        uint4 c4 = *reinterpret_cast<const uint4*>(yg + (size_t)f4 * SCH + q * 8);
        uint4 c5 = *reinterpret_cast<const uint4*>(yg + (size_t)f5 * SCH + q * 8);
        uint4 c6 = *reinterpret_cast<const uint4*>(yg + (size_t)f6 * SCH + q * 8);
        uint4 c7 = *reinterpret_cast<const uint4*>(yg + (size_t)f7 * SCH + q * 8);
        a0 = __hadd2(a0, u2h2(c0.x)); a1 = __hadd2(a1, u2h2(c0.y));
        a2 = __hadd2(a2, u2h2(c0.z)); a3 = __hadd2(a3, u2h2(c0.w));
        a0 = __hadd2(a0, u2h2(c1.x)); a1 = __hadd2(a1, u2h2(c1.y));
        a2 = __hadd2(a2, u2h2(c1.z)); a3 = __hadd2(a3, u2h2(c1.w));
        a0 = __hadd2(a0, u2h2(c2.x)); a1 = __hadd2(a1, u2h2(c2.y));
        a2 = __hadd2(a2, u2h2(c2.z)); a3 = __hadd2(a3, u2h2(c2.w));
        a0 = __hadd2(a0, u2h2(c3.x)); a1 = __hadd2(a1, u2h2(c3.y));
        a2 = __hadd2(a2, u2h2(c3.z)); a3 = __hadd2(a3, u2h2(c3.w));
        a0 = __hadd2(a0, u2h2(c4.x)); a1 = __hadd2(a1, u2h2(c4.y));
        a2 = __hadd2(a2, u2h2(c4.z)); a3 = __hadd2(a3, u2h2(c4.w));
        a0 = __hadd2(a0, u2h2(c5.x)); a1 = __hadd2(a1, u2h2(c5.y));
        a2 = __hadd2(a2, u2h2(c5.z)); a3 = __hadd2(a3, u2h2(c5.w));
        a0 = __hadd2(a0, u2h2(c6.x)); a1 = __hadd2(a1, u2h2(c6.y));
        a2 = __hadd2(a2, u2h2(c6.z)); a3 = __hadd2(a3, u2h2(c6.w));
        a0 = __hadd2(a0, u2h2(c7.x)); a1 = __hadd2(a1, u2h2(c7.y));
        a2 = __hadd2(a2, u2h2(c7.z)); a3 = __hadd2(a3, u2h2(c7.w));
    }
    // reduce over k (4 lanes)
    a0 = __hadd2(a0, u2h2(__shfl_xor(h22u(a0), 4, 64)));
    a1 = __hadd2(a1, u2h2(__shfl_xor(h22u(a1), 4, 64)));
    a2 = __hadd2(a2, u2h2(__shfl_xor(h22u(a2), 4, 64)));
    a3 = __hadd2(a3, u2h2(__shfl_xor(h22u(a3), 4, 64)));
    a0 = __hadd2(a0, u2h2(__shfl_xor(h22u(a0), 8, 64)));
    a1 = __hadd2(a1, u2h2(__shfl_xor(h22u(a1), 8, 64)));
    a2 = __hadd2(a2, u2h2(__shfl_xor(h22u(a2), 8, 64)));
    a3 = __hadd2(a3, u2h2(__shfl_xor(h22u(a3), 8, 64)));
    if ((lane & 12) == 0) {           // k==0 lanes: (np, q)
        float2 f0 = __half22float2(a0);
        float2 f1 = __half22float2(a1);
        float2 f2 = __half22float2(a2);
        float2 f3 = __half22float2(a3);
        f32x4 r0, r1;
        r0.x = fmaxf(f0.x, 0.f); r0.y = fmaxf(f0.y, 0.f);
        r0.z = fmaxf(f1.x, 0.f); r0.w = fmaxf(f1.y, 0.f);
        r1.x = fmaxf(f2.x, 0.f); r1.y = fmaxf(f2.y, 0.f);
        r1.z = fmaxf(f3.x, 0.f); r1.w = fmaxf(f3.y, 0.f);
        float* dst = out + (size_t)node * CH + g * SCH + q * 8;
        *reinterpret_cast<f32x4*>(dst)     = r0;
        *reinterpret_cast<f32x4*>(dst + 4) = r1;
    }
}

extern "C" void kernel_launch(void* const* d_in, const int* in_sizes, int n_in,
                              void* d_out, int out_size, void* d_ws, size_t ws_size,
                              hipStream_t stream) {
    const float* x  = (const float*)d_in[0];
    const int*   he = (const int*)d_in[1];
    const float* w  = (const float*)d_in[2];
    float* out = (float*)d_out;

    // workspace layout
    char* ws = (char*)d_ws;
    unsigned short* wt  = (unsigned short*)ws;                        // 131072 B
    unsigned short* es  = (unsigned short*)(ws + 131072);             // 10240000 B
    unsigned short* yb  = (unsigned short*)(ws + 10371072);           // 8*20001*32*2 = 10240512 B
    int* deg = (int*)(ws + 20611584);                                 // 200000 B
    unsigned short* ell = (unsigned short*)(ws + 20811584);           // 6400000 B

    // xb (fp16 x, sliced [8][N][32], 25.6 MB) lives inside d_out (51.2 MB f32)
    unsigned short* xb = (unsigned short*)d_out;

    hipMemsetAsync(deg, 0, (size_t)N_NODES * 4, stream);

    prep_kernel<<<CONV_BLOCKS + CH + 1, 256, 0, stream>>>(x, xb, w, wt, yb);

    gather_fill_kernel<<<FILL_BLOCKS + GATHER_BLOCKS, 256, 0, stream>>>(xb, he, es, deg, ell);

    {
        int blocks = (N_EDGES + 63) / 64;
        gemm_kernel<<<blocks, 256, 0, stream>>>(es, wt, yb);
    }

    apply_kernel<<<AP_BLOCKS, 256, 0, stream>>>(yb, deg, ell, out);
}

// Round 18
// 140.630 us; speedup vs baseline: 1.0871x; 1.0400x over previous
//
#include <hip/hip_runtime.h>
#include <hip/hip_bf16.h>
#include <hip/hip_fp16.h>

#define N_NODES 50000
#define N_EDGES 20000
#define EDGE_K  32
#define CH      256
#define N_INC   (N_EDGES * EDGE_K)   // 640000 incidences
#define ELL_CAP 64                   // max node degree capacity (Poisson(12.8))
#define NSLICE  8                    // channel slices == XCD count
#define SCH     32                   // channels per slice (32 x 2B = 64B rows)
#define ZROW    N_EDGES              // dedicated all-zeros yb row (clamp target)

typedef __attribute__((ext_vector_type(4))) float f32x4;
typedef __attribute__((ext_vector_type(8))) _Float16 f16x8;

static __device__ __forceinline__ __half2 u2h2(unsigned int u) {
    __half2 h; __builtin_memcpy(&h, &u, 4); return h;
}
static __device__ __forceinline__ unsigned int h22u(__half2 h) {
    unsigned int u; __builtin_memcpy(&u, &h, 4); return u;
}
static __device__ __forceinline__ unsigned int pk2h(float a, float b) {
    return h22u(__halves2half2(__float2half_rn(a), __float2half_rn(b)));
}

// Fused prep: x->fp16 sliced [8][N][32] | W^T fp16 | zero deg | ell := ZROW | yb zero-rows
#define CONV_BLOCKS (N_NODES * CH / 8 / 256)           // 6250
#define ZERO_BLOCKS ((N_NODES + 255) / 256)            // 196
#define ELLI_BLOCKS (N_NODES * ELL_CAP / 2 / 256)      // 6250 (uint writes)
__global__ void prep_kernel(const float* __restrict__ x, unsigned short* __restrict__ xb,
                            const float* __restrict__ w, unsigned short* __restrict__ wt,
                            int* __restrict__ deg, unsigned int* __restrict__ ellu,
                            unsigned short* __restrict__ yb) {
    int b = blockIdx.x;
    if (b < CONV_BLOCKS) {
        int i = b * 256 + threadIdx.x;        // one per 8 channels
        int n = i >> 5, sub = i & 31;
        int g = sub >> 2, cp = (sub & 3) * 8;
        const float* src = x + (size_t)n * CH + sub * 8;
        f32x4 v0 = *reinterpret_cast<const f32x4*>(src);
        f32x4 v1 = *reinterpret_cast<const f32x4*>(src + 4);
        uint4 u;
        u.x = pk2h(v0.x, v0.y);
        u.y = pk2h(v0.z, v0.w);
        u.z = pk2h(v1.x, v1.y);
        u.w = pk2h(v1.z, v1.w);
        *reinterpret_cast<uint4*>(xb + ((size_t)g * N_NODES + n) * SCH + cp) = u;
    } else if (b < CONV_BLOCKS + CH) {
        int n = b - CONV_BLOCKS;
        int k = threadIdx.x;
        __half h = __float2half_rn(w[k * CH + n]);
        wt[n * CH + k] = *reinterpret_cast<unsigned short*>(&h);
    } else if (b < CONV_BLOCKS + CH + ZERO_BLOCKS) {
        int i = (b - CONV_BLOCKS - CH) * 256 + threadIdx.x;
        if (i < N_NODES) deg[i] = 0;
    } else if (b < CONV_BLOCKS + CH + ZERO_BLOCKS + ELLI_BLOCKS) {
        int i = (b - CONV_BLOCKS - CH - ZERO_BLOCKS) * 256 + threadIdx.x;
        ellu[i] = 0x4E204E20u;   // two ushorts of 20000 == ZROW
    } else {
        // zero the dedicated yb zero-row for each slice (8 x 32 halves = 256)
        int g = threadIdx.x >> 5, c = threadIdx.x & 31;
        yb[((size_t)g * (N_EDGES + 1) + ZROW) * SCH + c] = 0;
    }
}

// Fused: ELL-fill (head, XCD-partitioned by node range) + sliced gather (tail).
// Gather wave = 4 edges x slice g=blockIdx%8 (pinned to XCD g; 3.2MB slice is
// L2-resident). Lanes (ep=l>>4, k=(l>>2)&3, q=l&3); 8 batched 16B loads,
// packed-fp16 accumulate, shfl_xor reduce over k.
#define FILL_GROUPS   8
#define NODES_PER_GRP (N_NODES / FILL_GROUPS)
#define FILL_WIN      2560
#define FILL_BLOCKS   ((N_INC / FILL_WIN) * FILL_GROUPS) // 2000
#define GGRP          (N_EDGES / 16)                     // 1250
#define GATHER_BLOCKS (GGRP * NSLICE)                    // 10000
__global__ __launch_bounds__(256, 4) void gather_fill_kernel(
        const unsigned short* __restrict__ xb, const int* __restrict__ he,
        unsigned short* __restrict__ es, int* __restrict__ deg,
        unsigned short* __restrict__ ell) {
    int b = blockIdx.x;
    if (b < FILL_BLOCKS) {
        int g  = b % FILL_GROUPS;
        int wn = b / FILL_GROUPS;
        int lo = g * NODES_PER_GRP, hi = lo + NODES_PER_GRP;
        int base = wn * FILL_WIN;
#pragma unroll
        for (int it = 0; it < FILL_WIN / 256; ++it) {
            int i = base + it * 256 + threadIdx.x;
            int node = he[i];
            if (node >= lo && node < hi) {
                int slot = atomicAdd(&deg[node], 1);
                if (slot < ELL_CAP)
                    ell[(size_t)node * ELL_CAP + slot] = (unsigned short)(i >> 5);
            }
        }
        return;
    }
    int gb  = b - FILL_BLOCKS;
    int g   = gb & 7;                 // slice == XCD (round-robin heuristic)
    int grp = gb >> 3;
    int w = threadIdx.x >> 6, lane = threadIdx.x & 63;
    int ebase = grp * 16 + w * 4;     // this wave's 4 edges
    const int* hp = he + (size_t)ebase * EDGE_K;
    int s = lane & 15;
    int ep = lane >> 4, k = (lane >> 2) & 3, q = lane & 3;
    int mA = hp[ep * 32 + s];         // edge ep, node slots 0..15
    int mB = hp[ep * 32 + 16 + s];    // edge ep, node slots 16..31
    const unsigned short* xg = xb + (size_t)g * N_NODES * SCH;
    int hb = lane & 48;
    // all 8 shuffles, then all 8 loads (batched for MLP), then packed adds
    int e0 = __shfl(mA, hb + ((0 + k) & 15), 64);
    int e1 = __shfl(mA, hb + ((4 + k) & 15), 64);
    int e2 = __shfl(mA, hb + ((8 + k) & 15), 64);
    int e3 = __shfl(mA, hb + ((12 + k) & 15), 64);
    int e4 = __shfl(mB, hb + ((0 + k) & 15), 64);
    int e5 = __shfl(mB, hb + ((4 + k) & 15), 64);
    int e6 = __shfl(mB, hb + ((8 + k) & 15), 64);
    int e7 = __shfl(mB, hb + ((12 + k) & 15), 64);
    uint4 d0 = *reinterpret_cast<const uint4*>(xg + (size_t)e0 * SCH + q * 8);
    uint4 d1 = *reinterpret_cast<const uint4*>(xg + (size_t)e1 * SCH + q * 8);
    uint4 d2 = *reinterpret_cast<const uint4*>(xg + (size_t)e2 * SCH + q * 8);
    uint4 d3 = *reinterpret_cast<const uint4*>(xg + (size_t)e3 * SCH + q * 8);
    uint4 d4 = *reinterpret_cast<const uint4*>(xg + (size_t)e4 * SCH + q * 8);
    uint4 d5 = *reinterpret_cast<const uint4*>(xg + (size_t)e5 * SCH + q * 8);
    uint4 d6 = *reinterpret_cast<const uint4*>(xg + (size_t)e6 * SCH + q * 8);
    uint4 d7 = *reinterpret_cast<const uint4*>(xg + (size_t)e7 * SCH + q * 8);
    __half2 a0 = u2h2(0u), a1 = u2h2(0u), a2 = u2h2(0u), a3 = u2h2(0u);
    a0 = __hadd2(a0, u2h2(d0.x)); a1 = __hadd2(a1, u2h2(d0.y));
    a2 = __hadd2(a2, u2h2(d0.z)); a3 = __hadd2(a3, u2h2(d0.w));
    a0 = __hadd2(a0, u2h2(d1.x)); a1 = __hadd2(a1, u2h2(d1.y));
    a2 = __hadd2(a2, u2h2(d1.z)); a3 = __hadd2(a3, u2h2(d1.w));
    a0 = __hadd2(a0, u2h2(d2.x)); a1 = __hadd2(a1, u2h2(d2.y));
    a2 = __hadd2(a2, u2h2(d2.z)); a3 = __hadd2(a3, u2h2(d2.w));
    a0 = __hadd2(a0, u2h2(d3.x)); a1 = __hadd2(a1, u2h2(d3.y));
    a2 = __hadd2(a2, u2h2(d3.z)); a3 = __hadd2(a3, u2h2(d3.w));
    a0 = __hadd2(a0, u2h2(d4.x)); a1 = __hadd2(a1, u2h2(d4.y));
    a2 = __hadd2(a2, u2h2(d4.z)); a3 = __hadd2(a3, u2h2(d4.w));
    a0 = __hadd2(a0, u2h2(d5.x)); a1 = __hadd2(a1, u2h2(d5.y));
    a2 = __hadd2(a2, u2h2(d5.z)); a3 = __hadd2(a3, u2h2(d5.w));
    a0 = __hadd2(a0, u2h2(d6.x)); a1 = __hadd2(a1, u2h2(d6.y));
    a2 = __hadd2(a2, u2h2(d6.z)); a3 = __hadd2(a3, u2h2(d6.w));
    a0 = __hadd2(a0, u2h2(d7.x)); a1 = __hadd2(a1, u2h2(d7.y));
    a2 = __hadd2(a2, u2h2(d7.z)); a3 = __hadd2(a3, u2h2(d7.w));
    // reduce over k (4 lanes)
    a0 = __hadd2(a0, u2h2(__shfl_xor(h22u(a0), 4, 64)));
    a1 = __hadd2(a1, u2h2(__shfl_xor(h22u(a1), 4, 64)));
    a2 = __hadd2(a2, u2h2(__shfl_xor(h22u(a2), 4, 64)));
    a3 = __hadd2(a3, u2h2(__shfl_xor(h22u(a3), 4, 64)));
    a0 = __hadd2(a0, u2h2(__shfl_xor(h22u(a0), 8, 64)));
    a1 = __hadd2(a1, u2h2(__shfl_xor(h22u(a1), 8, 64)));
    a2 = __hadd2(a2, u2h2(__shfl_xor(h22u(a2), 8, 64)));
    a3 = __hadd2(a3, u2h2(__shfl_xor(h22u(a3), 8, 64)));
    if ((lane & 12) == 0) {           // k==0 lanes: (ep, q)
        uint4 u;
        u.x = h22u(a0); u.y = h22u(a1); u.z = h22u(a2); u.w = h22u(a3);
        *reinterpret_cast<uint4*>(es + (size_t)(ebase + ep) * CH + g * SCH + q * 8) = u;
    }
}

// Y = es(fp16) @ W(fp16) via mfma_f32_16x16x32_f16; yb stored SLICED [8][E+1][32]
__global__ __launch_bounds__(256) void gemm_kernel(const unsigned short* __restrict__ es,
                                                   const unsigned short* __restrict__ wt,
                                                   unsigned short* __restrict__ yb) {
    int wid  = threadIdx.x >> 6;
    int lane = threadIdx.x & 63;
    int m0   = blockIdx.x * 64 + wid * 16;
    if (m0 >= N_EDGES) return;
    int lr = lane & 15;
    int lg = lane >> 4;

    f32x4 acc[16] = {};
    const unsigned short* arow = es + (size_t)(m0 + lr) * CH + lg * 8;
#pragma unroll
    for (int kk = 0; kk < CH; kk += 32) {
        f16x8 a = *reinterpret_cast<const f16x8*>(arow + kk);
#pragma unroll
        for (int nt = 0; nt < 16; ++nt) {
            f16x8 bb = *reinterpret_cast<const f16x8*>(
                wt + (size_t)(nt * 16 + lr) * CH + kk + lg * 8);
            acc[nt] = __builtin_amdgcn_mfma_f32_16x16x32_f16(a, bb, acc[nt], 0, 0, 0);
        }
    }
    // D layout: col = lane&15, row = (lane>>4)*4 + r  -> sliced write
#pragma unroll
    for (int nt = 0; nt < 16; ++nt) {
#pragma unroll
        for (int r = 0; r < 4; ++r) {
            int row = m0 + lg * 4 + r;
            __half h = __float2half_rn(acc[nt][r]);
            yb[((size_t)(nt >> 1) * (N_EDGES + 1) + row) * SCH + (nt & 1) * 16 + lr] =
                *reinterpret_cast<unsigned short*>(&h);
        }
    }
}

// out[n][g*32..] = relu( sum_j yb[g][ell[n][j]][:] ) -- sliced, XCD-pinned,
// zero-row-padded ELL -> unconditional batched loads, packed-fp16 accumulate.
#define AP_NPB    16                               // nodes per block (4 waves x 4)
#define AP_BLOCKS ((N_NODES / AP_NPB) * NSLICE)    // 25000
__global__ __launch_bounds__(256) void apply_kernel(
        const unsigned short* __restrict__ yb, const int* __restrict__ deg,
        const unsigned short* __restrict__ ell, float* __restrict__ out) {
    int b = blockIdx.x;
    int g = b & 7;                    // slice == XCD
    int w = threadIdx.x >> 6, lane = threadIdx.x & 63;
    int np = lane >> 4, s = lane & 15, k = (lane >> 2) & 3, q = lane & 3;
    int node = (b >> 3) * AP_NPB + w * 4 + np;     // exact cover
    int d = deg[node];
    if (d > ELL_CAP) d = ELL_CAP;
    const unsigned short* er = ell + (size_t)node * ELL_CAP;
    int m0 = er[s], m1 = er[16 + s], m2 = er[32 + s], m3 = er[48 + s];
    int dmax = d;
    dmax = max(dmax, __shfl_xor(dmax, 16, 64));
    dmax = max(dmax, __shfl_xor(dmax, 32, 64));    // wave-uniform max degree
    const unsigned short* yg = yb + (size_t)g * (N_EDGES + 1) * SCH;
    int hb = lane & 48;
    __half2 a0 = u2h2(0u), a1 = u2h2(0u), a2 = u2h2(0u), a3 = u2h2(0u);
    for (int rq = 0; rq < 4; ++rq) {
        if (rq * 16 >= dmax) break;                // uniform branch
        int m = (rq == 0) ? m0 : (rq == 1) ? m1 : (rq == 2) ? m2 : m3;
        int e0 = __shfl(m, hb + 0 + k, 64);
        int e1 = __shfl(m, hb + 4 + k, 64);
        int e2 = __shfl(m, hb + 8 + k, 64);
        int e3 = __shfl(m, hb + 12 + k, 64);
        uint4 d0 = *reinterpret_cast<const uint4*>(yg + (size_t)e0 * SCH + q * 8);
        uint4 d1 = *reinterpret_cast<const uint4*>(yg + (size_t)e1 * SCH + q * 8);
        uint4 d2 = *reinterpret_cast<const uint4*>(yg + (size_t)e2 * SCH + q * 8);
        uint4 d3 = *reinterpret_cast<const uint4*>(yg + (size_t)e3 * SCH + q * 8);
        a0 = __hadd2(a0, u2h2(d0.x)); a1 = __hadd2(a1, u2h2(d0.y));
        a2 = __hadd2(a2, u2h2(d0.z)); a3 = __hadd2(a3, u2h2(d0.w));
        a0 = __hadd2(a0, u2h2(d1.x)); a1 = __hadd2(a1, u2h2(d1.y));
        a2 = __hadd2(a2, u2h2(d1.z)); a3 = __hadd2(a3, u2h2(d1.w));
        a0 = __hadd2(a0, u2h2(d2.x)); a1 = __hadd2(a1, u2h2(d2.y));
        a2 = __hadd2(a2, u2h2(d2.z)); a3 = __hadd2(a3, u2h2(d2.w));
        a0 = __hadd2(a0, u2h2(d3.x)); a1 = __hadd2(a1, u2h2(d3.y));
        a2 = __hadd2(a2, u2h2(d3.z)); a3 = __hadd2(a3, u2h2(d3.w));
    }
    // reduce over k (4 lanes)
    a0 = __hadd2(a0, u2h2(__shfl_xor(h22u(a0), 4, 64)));
    a1 = __hadd2(a1, u2h2(__shfl_xor(h22u(a1), 4, 64)));
    a2 = __hadd2(a2, u2h2(__shfl_xor(h22u(a2), 4, 64)));
    a3 = __hadd2(a3, u2h2(__shfl_xor(h22u(a3), 4, 64)));
    a0 = __hadd2(a0, u2h2(__shfl_xor(h22u(a0), 8, 64)));
    a1 = __hadd2(a1, u2h2(__shfl_xor(h22u(a1), 8, 64)));
    a2 = __hadd2(a2, u2h2(__shfl_xor(h22u(a2), 8, 64)));
    a3 = __hadd2(a3, u2h2(__shfl_xor(h22u(a3), 8, 64)));
    if ((lane & 12) == 0) {           // k==0 lanes: (np, q)
        float2 f0 = __half22float2(a0);
        float2 f1 = __half22float2(a1);
        float2 f2 = __half22float2(a2);
        float2 f3 = __half22float2(a3);
        f32x4 r0, r1;
        r0.x = fmaxf(f0.x, 0.f); r0.y = fmaxf(f0.y, 0.f);
        r0.z = fmaxf(f1.x, 0.f); r0.w = fmaxf(f1.y, 0.f);
        r1.x = fmaxf(f2.x, 0.f); r1.y = fmaxf(f2.y, 0.f);
        r1.z = fmaxf(f3.x, 0.f); r1.w = fmaxf(f3.y, 0.f);
        float* dst = out + (size_t)node * CH + g * SCH + q * 8;
        *reinterpret_cast<f32x4*>(dst)     = r0;
        *reinterpret_cast<f32x4*>(dst + 4) = r1;
    }
}

extern "C" void kernel_launch(void* const* d_in, const int* in_sizes, int n_in,
                              void* d_out, int out_size, void* d_ws, size_t ws_size,
                              hipStream_t stream) {
    const float* x  = (const float*)d_in[0];
    const int*   he = (const int*)d_in[1];
    const float* w  = (const float*)d_in[2];
    float* out = (float*)d_out;

    // workspace layout
    char* ws = (char*)d_ws;
    unsigned short* wt  = (unsigned short*)ws;                        // 131072 B
    unsigned short* es  = (unsigned short*)(ws + 131072);             // 10240000 B
    unsigned short* yb  = (unsigned short*)(ws + 10371072);           // 8*(20001)*32*2 = 10240512 B
    int* deg = (int*)(ws + 20611584);                                 // 200000 B
    unsigned short* ell = (unsigned short*)(ws + 20811584);           // 6400000 B

    // xb (fp16 x, sliced [8][N][32], 25.6 MB) lives inside d_out (51.2 MB f32)
    unsigned short* xb = (unsigned short*)d_out;

    prep_kernel<<<CONV_BLOCKS + CH + ZERO_BLOCKS + ELLI_BLOCKS + 1, 256, 0, stream>>>(
        x, xb, w, wt, deg, (unsigned int*)ell, yb);

    gather_fill_kernel<<<FILL_BLOCKS + GATHER_BLOCKS, 256, 0, stream>>>(xb, he, es, deg, ell);

    {
        int blocks = (N_EDGES + 63) / 64;
        gemm_kernel<<<blocks, 256, 0, stream>>>(es, wt, yb);
    }

    apply_kernel<<<AP_BLOCKS, 256, 0, stream>>>(yb, deg, ell, out);
}